// Round 9
// baseline (97.877 us; speedup 1.0000x reference)
//
#include <hip/hip_runtime.h>
#include <hip/hip_bf16.h>

#define CELLS 1000   // 10*10*10
#define DPB   16     // depos per block in store kernel
#define WSTRIDE 32   // floats per depo in workspace: [0..29]=w, [30]=q, [31]=pad

// ---------------- Kernel A: per-depo weights -> workspace ----------------
// One thread per (depo,dim,k): 2 erfs. Writes w to ws[depo*32+dim*10+k],
// q to ws[depo*32+30], offsets to out_off. ~3e6 threads, ~3-4 us.
__global__ __launch_bounds__(256) void compute_w_kernel(
    const float* __restrict__ sigma,   // [N,3]
    const float* __restrict__ time,    // [N]
    const float* __restrict__ charge,  // [N]
    const float* __restrict__ tail,    // [N,3]
    const float* __restrict__ gs,      // [3]
    const float* __restrict__ nsig,    // [1]
    float* __restrict__ out_off,       // [N,3]
    float* __restrict__ ws,            // [N,32]
    int n)
{
    const int idx = blockIdx.x * blockDim.x + threadIdx.x;
    if (idx >= n * 30) return;
    const int depo = idx / 30;
    const int r    = idx - depo * 30;
    const int dim  = r / 10;
    const int k    = r - dim * 10;

    float c;
    if (dim == 0)      c = tail[depo * 3 + 1];
    else if (dim == 1) c = tail[depo * 3 + 2];
    else               c = time[depo];
    const float sg   = sigma[depo * 3 + dim];
    const float sp   = gs[dim];
    const float ns   = nsig[0];
    const float imin = floorf((c - ns * sg) / sp);
    const float inv  = 1.0f / (1.41421356237309f * sg);
    const float e0   = (imin + (float)k) * sp;
    const float cdf0 = 0.5f * (1.0f + erff((e0 - c) * inv));
    const float cdf1 = 0.5f * (1.0f + erff((e0 + sp - c) * inv));
    ws[depo * WSTRIDE + dim * 10 + k] = cdf1 - cdf0;
    if (k == 0) {
        out_off[(size_t)depo * 3 + dim] = (float)(int)imin;
        if (dim == 0) ws[depo * WSTRIDE + 30] = charge[depo];
    }
}

// ---------------- Kernel B: pure store stream ----------------
// 512 threads, 16 depos. Phase 1: ONE coalesced 4-B load + one ds_write per
// thread (ws slice for the block is contiguous 2 KB). Then the proven R2
// store phase. No erf, no scattered loads in this kernel's stream.
__global__ __launch_bounds__(512) void store_kernel(
    const float* __restrict__ ws,      // [N,32]
    float* __restrict__ out_r,         // [N,10,10,10]
    int n)
{
    const int d0  = blockIdx.x * DPB;
    const int tid = threadIdx.x;

    __shared__ float wq[DPB][WSTRIDE];

    const int lin = d0 * WSTRIDE + tid;            // block slice is contiguous
    if (lin < n * WSTRIDE)
        wq[tid >> 5][tid & 31] = ws[lin];
    __syncthreads();

    if (tid < 500) {
        const int half = (tid >= 250) ? 1 : 0;
        const int c4   = tid - 250 * half;
        const int cell0 = c4 * 4;

        int a0[4], a1[4], a2[4];
#pragma unroll
        for (int c = 0; c < 4; ++c) {
            const int cell = cell0 + c;
            a0[c] = cell / 100;
            a1[c] = 10 + (cell / 10) % 10;
            a2[c] = 20 + cell % 10;
        }

#pragma unroll
        for (int it = 0; it < DPB / 2; ++it) {
            const int d    = it * 2 + half;
            const int depo = d0 + d;
            if (depo < n) {
                const float q = wq[d][30];
                float4 v;
                v.x = q * wq[d][a0[0]] * wq[d][a1[0]] * wq[d][a2[0]];
                v.y = q * wq[d][a0[1]] * wq[d][a1[1]] * wq[d][a2[1]];
                v.z = q * wq[d][a0[2]] * wq[d][a1[2]] * wq[d][a2[2]];
                v.w = q * wq[d][a0[3]] * wq[d][a1[3]] * wq[d][a2[3]];
                float4* dst = reinterpret_cast<float4*>(out_r + (size_t)depo * CELLS) + c4;
                *dst = v;
            }
        }
    }
}

// ---------------- Fallback: single-kernel R2 (if ws too small) ----------------
__global__ __launch_bounds__(512) void raster_fused_kernel(
    const float* __restrict__ sigma, const float* __restrict__ time,
    const float* __restrict__ charge, const float* __restrict__ tail,
    const float* __restrict__ gs, const float* __restrict__ nsig,
    float* __restrict__ out_r, float* __restrict__ out_off, int n)
{
    const int d0  = blockIdx.x * DPB;
    const int tid = threadIdx.x;
    __shared__ float wq[DPB][32];

    if (tid < DPB * 30) {
        const int d   = tid / 30;
        const int r   = tid - d * 30;
        const int dim = r / 10;
        const int k   = r - dim * 10;
        const int depo = d0 + d;
        if (depo < n) {
            float c;
            if (dim == 0)      c = tail[depo * 3 + 1];
            else if (dim == 1) c = tail[depo * 3 + 2];
            else               c = time[depo];
            const float sg = sigma[depo * 3 + dim];
            const float sp = gs[dim];
            const float ns = nsig[0];
            const float imin = floorf((c - ns * sg) / sp);
            const float inv  = 1.0f / (1.41421356237309f * sg);
            const float e0 = (imin + (float)k) * sp;
            const float cdf0 = 0.5f * (1.0f + erff((e0 - c) * inv));
            const float cdf1 = 0.5f * (1.0f + erff((e0 + sp - c) * inv));
            wq[d][dim * 10 + k] = cdf1 - cdf0;
            if (k == 0) {
                out_off[(size_t)depo * 3 + dim] = (float)(int)imin;
                if (dim == 0) wq[d][30] = charge[depo];
            }
        }
    }
    __syncthreads();

    if (tid < 500) {
        const int half = (tid >= 250) ? 1 : 0;
        const int c4   = tid - 250 * half;
        int a0[4], a1[4], a2[4];
#pragma unroll
        for (int c = 0; c < 4; ++c) {
            const int cell = c4 * 4 + c;
            a0[c] = cell / 100;
            a1[c] = 10 + (cell / 10) % 10;
            a2[c] = 20 + cell % 10;
        }
#pragma unroll
        for (int it = 0; it < DPB / 2; ++it) {
            const int d    = it * 2 + half;
            const int depo = d0 + d;
            if (depo < n) {
                const float q = wq[d][30];
                float4 v;
                v.x = q * wq[d][a0[0]] * wq[d][a1[0]] * wq[d][a2[0]];
                v.y = q * wq[d][a0[1]] * wq[d][a1[1]] * wq[d][a2[1]];
                v.z = q * wq[d][a0[2]] * wq[d][a1[2]] * wq[d][a2[2]];
                v.w = q * wq[d][a0[3]] * wq[d][a1[3]] * wq[d][a2[3]];
                float4* dst = reinterpret_cast<float4*>(out_r + (size_t)depo * CELLS) + c4;
                *dst = v;
            }
        }
    }
}

extern "C" void kernel_launch(void* const* d_in, const int* in_sizes, int n_in,
                              void* d_out, int out_size, void* d_ws, size_t ws_size,
                              hipStream_t stream) {
    const float* sigma  = (const float*)d_in[0];  // [N,3]
    const float* time_  = (const float*)d_in[1];  // [N]
    const float* charge = (const float*)d_in[2];  // [N]
    const float* tail   = (const float*)d_in[3];  // [N,3]
    const float* gs     = (const float*)d_in[4];  // [3]
    const float* nsig   = (const float*)d_in[5];  // [1]

    const int n = in_sizes[1];  // time has N elements

    float* out_r   = (float*)d_out;                       // N*1000 floats
    float* out_off = (float*)d_out + (size_t)n * CELLS;   // N*3 values

    const size_t ws_needed = (size_t)n * WSTRIDE * sizeof(float);
    if (ws_size >= ws_needed) {
        float* ws = (float*)d_ws;
        const int ta = n * 30;
        compute_w_kernel<<<(ta + 255) / 256, 256, 0, stream>>>(
            sigma, time_, charge, tail, gs, nsig, out_off, ws, n);
        const int grid = (n + DPB - 1) / DPB;
        store_kernel<<<grid, 512, 0, stream>>>(ws, out_r, n);
    } else {
        const int grid = (n + DPB - 1) / DPB;
        raster_fused_kernel<<<grid, 512, 0, stream>>>(
            sigma, time_, charge, tail, gs, nsig, out_r, out_off, n);
    }
}

// Round 10
// 85.492 us; speedup vs baseline: 1.1449x; 1.1449x over previous
//
#include <hip/hip_runtime.h>
#include <hip/hip_bf16.h>

#define CELLS 1000    // 10*10*10
#define DPB   32      // depos per block: 32*4000B = 128000B = 125 x 1024B (aligned!)
#define NTH   512
#define F4PB  8000    // float4 per block = DPB*1000/4

// Flat, store-aligned kernel. Block owns a 128000-byte output span (32 depos)
// whose base is 1024B-aligned, so EVERY wave-store instruction writes one
// aligned 1024B segment (8 full cache lines, no partial sectors) -- the one
// structural property all previous variants lacked vs fillBuffer.
// Phase 1: 960 (depo,dim,k) tasks over 512 threads -> wq[32][32] in LDS.
// Store : thread t stores global float4 (block_base + i*512 + t), i=0..15;
//         per-f4 indices (d, c4, cell components) recomputed (~40 VALU).
__global__ __launch_bounds__(NTH) void raster_kernel(
    const float* __restrict__ sigma,   // [N,3]
    const float* __restrict__ time,    // [N]
    const float* __restrict__ charge,  // [N]
    const float* __restrict__ tail,    // [N,3]
    const float* __restrict__ gs,      // [3]
    const float* __restrict__ nsig,    // [1]
    float* __restrict__ out_r,         // [N,10,10,10]
    float* __restrict__ out_off,       // [N,3] (int values stored as f32)
    int n)
{
    const int d0  = blockIdx.x * DPB;
    const int tid = threadIdx.x;

    __shared__ float wq[DPB][32];   // [d][0..29]=w, [30]=charge

    // ---- phase 1: weights ----
#pragma unroll
    for (int idx = tid; idx < DPB * 30; idx += NTH) {
        const int d   = idx / 30;
        const int r   = idx - d * 30;
        const int dim = r / 10;
        const int k   = r - dim * 10;
        const int depo = d0 + d;
        if (depo < n) {
            float c;
            if (dim == 0)      c = tail[depo * 3 + 1];
            else if (dim == 1) c = tail[depo * 3 + 2];
            else               c = time[depo];
            const float sg   = sigma[depo * 3 + dim];
            const float sp   = gs[dim];
            const float ns   = nsig[0];
            const float imin = floorf((c - ns * sg) / sp);
            const float inv  = 1.0f / (1.41421356237309f * sg);
            const float e0   = (imin + (float)k) * sp;
            const float cdf0 = 0.5f * (1.0f + erff((e0 - c) * inv));
            const float cdf1 = 0.5f * (1.0f + erff((e0 + sp - c) * inv));
            wq[d][dim * 10 + k] = cdf1 - cdf0;
            if (k == 0) {
                out_off[(size_t)depo * 3 + dim] = (float)(int)imin;
                if (dim == 0) wq[d][30] = charge[depo];
            }
        }
    }
    __syncthreads();

    // ---- store phase: aligned flat stores ----
    // valid float4 count in this block (handles ragged tail generally)
    int valid = (n - d0) * 250;
    if (valid > F4PB) valid = F4PB;

    float4* const dstbase = reinterpret_cast<float4*>(out_r) + (size_t)blockIdx.x * F4PB;

#pragma unroll
    for (int i = 0; i < 16; ++i) {
        const int j = i * NTH + tid;           // local float4 index, wave-aligned
        if (j < valid) {
            const int d    = j / 250;          // depo within block
            const int c4   = j - d * 250;
            const int cell0 = c4 * 4;
            const int a0   = cell0 / 100;      // constant across the 4 cells
            const float q   = wq[d][30];
            const float w0q = q * wq[d][a0];

            float4 v;
            {
                const int cell = cell0 + 0;
                const int t10  = cell / 10;
                v.x = w0q * wq[d][10 + (t10 - 10 * a0)] * wq[d][20 + (cell - 10 * t10)];
            }
            {
                const int cell = cell0 + 1;
                const int t10  = cell / 10;
                v.y = w0q * wq[d][10 + (t10 - 10 * a0)] * wq[d][20 + (cell - 10 * t10)];
            }
            {
                const int cell = cell0 + 2;
                const int t10  = cell / 10;
                v.z = w0q * wq[d][10 + (t10 - 10 * a0)] * wq[d][20 + (cell - 10 * t10)];
            }
            {
                const int cell = cell0 + 3;
                const int t10  = cell / 10;
                v.w = w0q * wq[d][10 + (t10 - 10 * a0)] * wq[d][20 + (cell - 10 * t10)];
            }
            dstbase[j] = v;
        }
    }
}

extern "C" void kernel_launch(void* const* d_in, const int* in_sizes, int n_in,
                              void* d_out, int out_size, void* d_ws, size_t ws_size,
                              hipStream_t stream) {
    const float* sigma  = (const float*)d_in[0];  // [N,3]
    const float* time_  = (const float*)d_in[1];  // [N]
    const float* charge = (const float*)d_in[2];  // [N]
    const float* tail   = (const float*)d_in[3];  // [N,3]
    const float* gs     = (const float*)d_in[4];  // [3]
    const float* nsig   = (const float*)d_in[5];  // [1]

    const int n = in_sizes[1];  // time has N elements

    float* out_r   = (float*)d_out;                       // N*1000 floats
    float* out_off = (float*)d_out + (size_t)n * CELLS;   // N*3 values

    const int grid = (n + DPB - 1) / DPB;
    raster_kernel<<<grid, NTH, 0, stream>>>(sigma, time_, charge, tail, gs, nsig,
                                            out_r, out_off, n);
}

// Round 11
// 83.748 us; speedup vs baseline: 1.1687x; 1.0208x over previous
//
#include <hip/hip_runtime.h>
#include <hip/hip_bf16.h>

#define PATCH 10
#define CELLS 1000   // 10*10*10
#define DPB   16     // depos per block (100000 % 16 == 0 -> 6250 blocks)

typedef float vfloat4 __attribute__((ext_vector_type(4)));

// Best-measured variant (R2, 81.55 us = 4.93 TB/s effective on 401 MB output).
// 512 threads, 16 depos per block.
// Phase 1: threads 0..479 -> one (depo,dim,k) each: compute w[d][dim*10+k]
//          (2 erfs), k==0 threads also write offsets; (dim==0,k==0) loads q.
// Phase 2: threads 0..499 -> 8 unrolled iterations; thread owns a fixed
//          float4 cell-group (indices precomputed once), iterates over depos.
//          32 KB of nontemporal float4 stores per block.
//
// Falsified alternatives (all 82-89 us): persistent+dbuf+raw-barrier (R3),
// fewer LDS reads per float4 (R4), plain vs NT stores (R5), 200KB bursts
// (R6), zero-barrier wave-autonomous (R7), two-kernel pure-store split (R8),
// 1024B-aligned flat wave stores (R9). Remaining gap to fillBuffer's 7 TB/s
// attributed to launch/ramp overhead on a 401 MB (82 us) kernel -- write-
// byte-bound structural floor.
__global__ __launch_bounds__(512) void raster_kernel(
    const float* __restrict__ sigma,   // [N,3]
    const float* __restrict__ time,    // [N]
    const float* __restrict__ charge,  // [N]
    const float* __restrict__ tail,    // [N,3]
    const float* __restrict__ gs,      // [3]
    const float* __restrict__ nsig,    // [1]
    float* __restrict__ out_r,         // [N,10,10,10]
    float* __restrict__ out_off,       // [N,3] (int values stored as f32)
    int n)
{
    const int d0  = blockIdx.x * DPB;
    const int tid = threadIdx.x;

    __shared__ float wq[DPB][32];   // [d][0..29]=w, [30]=charge

    if (tid < DPB * 30) {
        const int d   = tid / 30;
        const int r   = tid - d * 30;
        const int dim = r / 10;
        const int k   = r - dim * 10;
        const int depo = d0 + d;
        if (depo < n) {
            float c;
            if (dim == 0)      c = tail[depo * 3 + 1];
            else if (dim == 1) c = tail[depo * 3 + 2];
            else               c = time[depo];
            const float sg = sigma[depo * 3 + dim];
            const float sp = gs[dim];
            const float ns = nsig[0];
            const float imin = floorf((c - ns * sg) / sp);
            const float inv  = 1.0f / (1.41421356237309f * sg);
            const float e0 = (imin + (float)k) * sp;
            const float cdf0 = 0.5f * (1.0f + erff((e0 - c) * inv));
            const float cdf1 = 0.5f * (1.0f + erff((e0 + sp - c) * inv));
            wq[d][dim * 10 + k] = cdf1 - cdf0;
            if (k == 0) {
                out_off[(size_t)depo * 3 + dim] = (float)(int)imin;
                if (dim == 0) wq[d][30] = charge[depo];
            }
        }
    }
    __syncthreads();

    if (tid < 500) {
        const int half = (tid >= 250) ? 1 : 0;
        const int c4   = tid - 250 * half;       // float4 index within depo
        const int cell0 = c4 * 4;

        // Per-component w indices, fixed for this thread across all depos.
        int a0[4], a1[4], a2[4];
#pragma unroll
        for (int c = 0; c < 4; ++c) {
            const int cell = cell0 + c;
            a0[c] = cell / 100;
            a1[c] = 10 + (cell / 10) % 10;
            a2[c] = 20 + cell % 10;
        }

#pragma unroll
        for (int it = 0; it < DPB / 2; ++it) {
            const int d    = it * 2 + half;
            const int depo = d0 + d;
            if (depo < n) {
                const float q = wq[d][30];
                vfloat4 v;
                v.x = q * wq[d][a0[0]] * wq[d][a1[0]] * wq[d][a2[0]];
                v.y = q * wq[d][a0[1]] * wq[d][a1[1]] * wq[d][a2[1]];
                v.z = q * wq[d][a0[2]] * wq[d][a1[2]] * wq[d][a2[2]];
                v.w = q * wq[d][a0[3]] * wq[d][a1[3]] * wq[d][a2[3]];
                vfloat4* dst = reinterpret_cast<vfloat4*>(out_r + (size_t)depo * CELLS) + c4;
                __builtin_nontemporal_store(v, dst);
            }
        }
    }
}

extern "C" void kernel_launch(void* const* d_in, const int* in_sizes, int n_in,
                              void* d_out, int out_size, void* d_ws, size_t ws_size,
                              hipStream_t stream) {
    const float* sigma  = (const float*)d_in[0];  // [N,3]
    const float* time_  = (const float*)d_in[1];  // [N]
    const float* charge = (const float*)d_in[2];  // [N]
    const float* tail   = (const float*)d_in[3];  // [N,3]
    const float* gs     = (const float*)d_in[4];  // [3]
    const float* nsig   = (const float*)d_in[5];  // [1]

    const int n = in_sizes[1];  // time has N elements

    float* out_r   = (float*)d_out;                       // N*1000 floats
    float* out_off = (float*)d_out + (size_t)n * CELLS;   // N*3 values

    const int grid = (n + DPB - 1) / DPB;
    raster_kernel<<<grid, 512, 0, stream>>>(sigma, time_, charge, tail, gs, nsig,
                                            out_r, out_off, n);
}